// Round 8
// baseline (4025.115 us; speedup 1.0000x reference)
//
#include <hip/hip_runtime.h>
#include <hip/hip_fp16.h>

typedef unsigned int u32;

// Soft-DTW fwd, T=4096, D=16, gamma=1. fp32 DP in log2 domain, carried as an
// UNNORMALIZED logsumexp pair (m, w): R' = m - log2(w), R = R'*ln2.
// Cell: mu = min3(m_u, m_d, m_l); w_new = sum_t w_t * 2^(mu - m_t);
// m_new = d' + mu. No log in the serial chain (m-chain: min3+add; w-chain:
// fma); the 3 exp2's are off-chain. Fold m += log2(w), w = 1 every 4 groups.
// 16 blocks x 4 waves x 64 lanes, 1 row/lane, 1 wave/SIMD. Lane l at local
// step s computes column j = s - l; intra-wave handoff via DPP wave_shr1.
// Wave-to-wave handoff: full-row single-write rings (48 hops LDS, 15 global),
// per-step publication of folded r via volatile stores; consumers use
// sentinel verify + spin (LDS volatile / global agent-atomic loads).
// Ring prefetch 2 groups, Et (fp16 d'*log2e) prefetch 4 groups, modulo-phase.

constexpr int   kN      = 4096;
constexpr int   kLanes  = 64;
constexpr int   kWaves  = 4;               // per block (1 per SIMD)
constexpr int   kBlocks = 16;
constexpr int   kSMax   = kN + kLanes;     // 4160 local steps
constexpr int   kG      = 8;               // steps per group
constexpr int   kGroups = kSMax / kG;      // 520
constexpr u32   kSent   = 0xFFFFFFFFu;     // NaN pattern, never a real value
constexpr float kBigP   = 1.4426950408889634e10f;   // 1e10 * log2e
constexpr float kLog2e  = 1.4426950408889634f;
constexpr float kLn2    = 0.6931471805599453f;
constexpr int   kGRS    = kSMax + 64;      // global ring stride (u32) = 4224
constexpr int   kGRTot  = (kBlocks - 1) * kGRS;
constexpr int   kLRS    = 4208;            // LDS ring stride (u32)
constexpr int   kLdsTot = (kWaves - 1) * kLRS;   // 12624 u32 = 50.5 KB

#if __has_builtin(__builtin_amdgcn_exp2f)
#define EXP2F(x) __builtin_amdgcn_exp2f(x)
#else
#define EXP2F(x) exp2f(x)
#endif
#if __has_builtin(__builtin_amdgcn_logf)
#define LOG2F(x) __builtin_amdgcn_logf(x)
#else
#define LOG2F(x) log2f(x)
#endif

__device__ __forceinline__ float dppShr1f(float v) {
  // wave_shr1: lane l <- lane l-1; lane 0 keeps old(=0), cndmask'd at use
  return __int_as_float(__builtin_amdgcn_update_dpp(0, __float_as_int(v), 0x138, 0xF, 0xF, false));
}

__device__ __forceinline__ u32 aloadG(const u32* p) {
  return __hip_atomic_load(p, __ATOMIC_RELAXED, __HIP_MEMORY_SCOPE_AGENT);
}
__device__ __forceinline__ u32 aloadL(const u32* p) {
  return __hip_atomic_load(p, __ATOMIC_RELAXED, __HIP_MEMORY_SCOPE_WORKGROUP);
}

__global__ __launch_bounds__(256) void sdtw_prep(const float* __restrict__ A,
                                                 const float* __restrict__ B,
                                                 uint4* __restrict__ Et,
                                                 u32* __restrict__ gring) {
  const int tid = threadIdx.x;
  const int w   = blockIdx.y;                         // band 0..63
  const int gid = ((w * (int)gridDim.x + (int)blockIdx.x) << 8) + tid;
  if (gid < kGRTot) gring[gid] = kSent;

  const int l   = tid & 63;
  const int grp = (int)blockIdx.x * 4 + (tid >> 6);

  const float4* Ap = (const float4*)(A + (size_t)(w * 64 + l) * 16);
  const float4 a0 = Ap[0], a1 = Ap[1], a2 = Ap[2], a3 = Ap[3];
  auto sq = [](float4 a, float4 b) {
    const float dx = a.x - b.x, dy = a.y - b.y, dz = a.z - b.z, dw = a.w - b.w;
    return fmaf(dx, dx, fmaf(dy, dy, fmaf(dz, dz, dw * dw)));
  };
  u32 hp[4];
#pragma unroll
  for (int pr = 0; pr < 4; ++pr) {
    float dv[2];
#pragma unroll
    for (int h = 0; h < 2; ++h) {
      const int q = pr * 2 + h;
      const int s = grp * kG + q + 1;
      const int jb = min(max(s - l - 1, 0), kN - 1);
      const float4* Bp = (const float4*)(B + (size_t)jb * 16);
      dv[h] = (sq(a0, Bp[0]) + sq(a1, Bp[1]) + sq(a2, Bp[2]) + sq(a3, Bp[3])) * kLog2e;
    }
    hp[pr] = ((u32)__half_as_ushort(__float2half(dv[1])) << 16)
           |  (u32)__half_as_ushort(__float2half(dv[0]));
  }
  Et[((size_t)w * kGroups + grp) * 64 + l] = make_uint4(hp[0], hp[1], hp[2], hp[3]);
}

template <bool MASK>
__device__ __forceinline__ void run(
    int gBeg, int gEnd, int l, int v, int b,
    const uint4* __restrict__ EtL,
    const u32* __restrict__ gin, u32* __restrict__ gout,
    const u32* __restrict__ lin, u32* __restrict__ lout,
    float& mp, float& wp, float& mdm, float& wdm,
    u32 (&c)[2][kG], uint4 (&e4)[4],
    float* __restrict__ out) {
  const bool consG    = (v == 0) && (b > 0);
  const bool consNone = (v == 0) && (b == 0);
  const bool consL    = (v > 0);
  const bool prodL    = (v < kWaves - 1);
  const bool prodG    = (v == kWaves - 1) && (b < kBlocks - 1);
  const bool isL0  = (l == 0);
  const bool isL63 = (l == kLanes - 1);

  for (int g4 = gBeg; g4 < gEnd; g4 += 4) {
#pragma unroll
    for (int ph = 0; ph < 4; ++ph) {
      const int g = g4 + ph;
      const int ri = g & 1;                     // ring phase
      const int ei = g & 3;                     // Et phase

      // ---- verify this group's poll slots (wave-uniform; rare slow path) ----
      if (!consNone) {
        u32 mm = c[ri][0];
#pragma unroll
        for (int q = 1; q < kG; ++q) mm = mm > c[ri][q] ? mm : c[ri][q];
        if (mm == kSent) {
#pragma unroll
          for (int q = 0; q < kG; ++q) {
            const int e = g * kG + q;
            if (!MASK || e < kN) {
              u32 vv = c[ri][q];
              if (consG) { while (vv == kSent) vv = aloadG(gin + e); }
              else       { while (vv == kSent) vv = aloadL(lin + e); }
              c[ri][q] = vv;
            }
          }
        }
      }

      // ---- 8 cells ----
      const u32 ecs[4] = {e4[ei].x, e4[ei].y, e4[ei].z, e4[ei].w};
#pragma unroll
      for (int q = 0; q < kG; ++q) {
        const int s = g * kG + q + 1;
        // up pair from lane l-1; lane 0 injects (r, 1)
        float mu_ = dppShr1f(mp);
        float wu_ = dppShr1f(wp);
        const float injm = consNone ? kBigP : __uint_as_float(c[ri][q]);
        mu_ = isL0 ? injm : mu_;
        wu_ = isL0 ? 1.0f : wu_;

        u32 hw = ecs[q >> 1];
        if (q & 1) hw >>= 16;
        const float dpv = __half2float(__ushort_as_half((unsigned short)(hw & 0xFFFFu)));

        const float mu = fminf(fminf(mu_, mdm), mp);     // v_min3
        const float pu = EXP2F(mu - mu_);
        const float pd = EXP2F(mu - mdm);
        const float pl = EXP2F(mu - mp);
        float wn = fmaf(wu_, pu, fmaf(wdm, pd, wp * pl));
        float mn = dpv + mu;
        if (MASK) {
          const int j = s - l;
          const bool jv = (j >= 1) && (j <= kN);
          mn = jv ? mn : kBigP;
          wn = jv ? wn : 1.0f;
        }
        mdm = mu_; wdm = wu_;
        mp = mn; wp = wn;

        if (prodL || prodG) {
          const float r = mn - LOG2F(wn);                // fold for publish (off-chain)
          if (isL63) {
            int e = s - kLanes;
            if (MASK) { const bool ok = (e >= 0) && (e < kN); e = ok ? e : kSMax; }
            if (prodL) *(volatile u32*)(lout + e) = __float_as_uint(r);
            else       *(volatile u32*)(gout + e) = __float_as_uint(r);
          }
        } else if (MASK) {
          if (isL63 && s == kN + kLanes - 1)
            out[0] = (mn - LOG2F(wn)) * kLn2;            // R[4096,4096]
        }
      }

      // ---- fold state every 4 groups (w <= 3^33 stays in fp32 range) ----
      if (ph == 3) {
        mp  += LOG2F(wp);  wp  = 1.0f;
        mdm += LOG2F(wdm); wdm = 1.0f;
      }

      // ---- prefetch: ring for g+2 (same parity), Et for g+4 ----
      {
        const int gr = g + 2;
        const int eb = gr * kG;                          // <= 4168, in-ring
        if (consG) {
#pragma unroll
          for (int q = 0; q < kG; ++q) c[ri][q] = aloadG(gin + eb + q);
        } else if (consL) {
#pragma unroll
          for (int q = 0; q < kG; ++q) c[ri][q] = aloadL(lin + eb + q);
        }
        const int ge = g + 4;
        const int gc = ge < kGroups ? ge : kGroups - 1;
        e4[ei] = EtL[(size_t)gc * 64];
      }
    }
  }
}

__global__ __launch_bounds__(kWaves * kLanes) void sdtw_dp(const uint4* __restrict__ Et,
                                                           u32* __restrict__ gring,
                                                           float* __restrict__ out) {
  const int tid = threadIdx.x;
  const int v = tid >> 6, l = tid & 63;
  const int b = blockIdx.x;
  const int W = b * kWaves + v;                 // band 0..63 (row = 64W + l + 1)

  __shared__ u32 ring[kLdsTot];
  for (int i = tid; i < kLdsTot; i += kWaves * kLanes) ring[i] = kSent;
  __syncthreads();

  const uint4* EtL = Et + (size_t)W * kGroups * 64 + l;
  const u32* gin = gring + (size_t)(b > 0 ? b - 1 : 0) * kGRS;
  u32* gout = gring + (size_t)(b < kBlocks - 1 ? b : 0) * kGRS;
  const u32* lin = ring + (v > 0 ? v - 1 : 0) * kLRS;
  u32* lout = ring + (v < kWaves - 1 ? v : 0) * kLRS;

  // state pairs: left (mp,wp), diag (mdm,wdm); R' = m - log2(w)
  float mp  = kBigP, wp  = 1.0f;
  float mdm = (W == 0 && l == 0) ? 0.0f : kBigP;
  float wdm = 1.0f;

  const bool consG = (v == 0) && (b > 0);
  const bool consL = (v > 0);
  u32 c[2][kG];
  uint4 e4[4];
#pragma unroll
  for (int ph = 0; ph < 4; ++ph) e4[ph] = EtL[(size_t)ph * 64];
#pragma unroll
  for (int ri = 0; ri < 2; ++ri) {
#pragma unroll
    for (int q = 0; q < kG; ++q) {
      const int e = ri * kG + q;
      u32 val = __float_as_uint(kBigP);
      if (consG)      val = aloadG(gin + e);
      else if (consL) val = aloadL(lin + e);
      c[ri][q] = val;
    }
  }

  run<true >(0,   8,       l, v, b, EtL, gin, gout, lin, lout, mp, wp, mdm, wdm, c, e4, out);
  run<false>(8,   512,     l, v, b, EtL, gin, gout, lin, lout, mp, wp, mdm, wdm, c, e4, out);
  run<true >(512, kGroups, l, v, b, EtL, gin, gout, lin, lout, mp, wp, mdm, wdm, c, e4, out);
}

extern "C" void kernel_launch(void* const* d_in, const int* in_sizes, int n_in,
                              void* d_out, int out_size, void* d_ws, size_t ws_size,
                              hipStream_t stream) {
  const float* A = (const float*)d_in[0];
  const float* B = (const float*)d_in[1];
  float* out = (float*)d_out;

  u32* gring = (u32*)d_ws;
  uint4* Et = (uint4*)(gring + kGRTot);
  // ws need: 15*4224*4 B + 64*520*64*16 B ~= 0.25 MB + 34.1 MB (fits, per R2)

  sdtw_prep<<<dim3(kGroups / 4, 64), 256, 0, stream>>>(A, B, Et, gring);
  sdtw_dp<<<kBlocks, kWaves * kLanes, 0, stream>>>(Et, gring, out);
}

// Round 9
// 1283.275 us; speedup vs baseline: 3.1366x; 3.1366x over previous
//
#include <hip/hip_runtime.h>
#include <hip/hip_fp16.h>

typedef unsigned int u32;

// Soft-DTW fwd, T=4096, D=16, gamma=1. fp32 DP in log2 domain, carried as an
// UNNORMALIZED logsumexp pair (m, w): R' = m - log2(w), R = R'*ln2.
// Cell: mu = min3(m_u, m_d, m_l); w_new = sum_t w_t * 2^(mu - m_t);
// m_new = d' + mu. No log in the serial chain (m-chain: min3+add ~16cyc;
// w-chain: fma ~12cyc); the 3 exp2's hang off the fast m-chain. Fold
// m += log2(w), w = 1 every 4 groups (amortized ~1 cyc/step).
// 16 blocks x 4 waves x 64 lanes, 1 row/lane, 1 wave/SIMD. Lane l at local
// step s computes column j = s - l; intra-wave handoff via DPP wave_shr1.
// Wave-to-wave handoff: full-row single-write rings; producers publish the
// FOLDED scalar r = m - log2(w) per step (log is off-chain, issue-only).
// CRITICAL (R7/R8 lesson): global-ring stores MUST be agent-scope atomics —
// plain volatile stores sit in the producer XCD's L2 and consumers on other
// XCDs stall ~ms until writeback. LDS rings use workgroup atomics.
// Prefetch: ring 2 groups, Et (fp16 d'*log2e) 4 groups, modulo-phase regs;
// sched_barrier at phase end keeps prefetch issue far from the verify wait.

constexpr int   kN      = 4096;
constexpr int   kLanes  = 64;
constexpr int   kWaves  = 4;               // per block (1 per SIMD)
constexpr int   kBlocks = 16;
constexpr int   kSMax   = kN + kLanes;     // 4160 local steps
constexpr int   kG      = 8;               // steps per group
constexpr int   kGroups = kSMax / kG;      // 520
constexpr u32   kSent   = 0xFFFFFFFFu;     // NaN pattern, never a real value
constexpr float kBigP   = 1.4426950408889634e10f;   // 1e10 * log2e
constexpr float kLog2e  = 1.4426950408889634f;
constexpr float kLn2    = 0.6931471805599453f;
constexpr int   kGRS    = kSMax + 64;      // global ring stride (u32) = 4224
constexpr int   kGRTot  = (kBlocks - 1) * kGRS;
constexpr int   kLRS    = 4208;            // LDS ring stride (u32)
constexpr int   kLdsTot = (kWaves - 1) * kLRS;   // 12624 u32 = 50.5 KB

#if __has_builtin(__builtin_amdgcn_exp2f)
#define EXP2F(x) __builtin_amdgcn_exp2f(x)
#else
#define EXP2F(x) exp2f(x)
#endif
#if __has_builtin(__builtin_amdgcn_logf)
#define LOG2F(x) __builtin_amdgcn_logf(x)
#else
#define LOG2F(x) log2f(x)
#endif

#if __has_builtin(__builtin_amdgcn_sched_barrier)
#define SCHED_FENCE() __builtin_amdgcn_sched_barrier(0)
#else
#define SCHED_FENCE()
#endif

__device__ __forceinline__ float dppShr1f(float v) {
  // wave_shr1: lane l <- lane l-1; lane 0 keeps old(=0), cndmask'd at use
  return __int_as_float(__builtin_amdgcn_update_dpp(0, __float_as_int(v), 0x138, 0xF, 0xF, false));
}

__device__ __forceinline__ u32 aloadG(const u32* p) {
  return __hip_atomic_load(p, __ATOMIC_RELAXED, __HIP_MEMORY_SCOPE_AGENT);
}
__device__ __forceinline__ void astoreG(u32* p, u32 v) {
  __hip_atomic_store(p, v, __ATOMIC_RELAXED, __HIP_MEMORY_SCOPE_AGENT);
}
__device__ __forceinline__ u32 aloadL(const u32* p) {
  return __hip_atomic_load(p, __ATOMIC_RELAXED, __HIP_MEMORY_SCOPE_WORKGROUP);
}
__device__ __forceinline__ void astoreL(u32* p, u32 v) {
  __hip_atomic_store(p, v, __ATOMIC_RELAXED, __HIP_MEMORY_SCOPE_WORKGROUP);
}

__global__ __launch_bounds__(256) void sdtw_prep(const float* __restrict__ A,
                                                 const float* __restrict__ B,
                                                 uint4* __restrict__ Et,
                                                 u32* __restrict__ gring) {
  const int tid = threadIdx.x;
  const int w   = blockIdx.y;                         // band 0..63
  const int gid = ((w * (int)gridDim.x + (int)blockIdx.x) << 8) + tid;
  if (gid < kGRTot) gring[gid] = kSent;

  const int l   = tid & 63;
  const int grp = (int)blockIdx.x * 4 + (tid >> 6);

  const float4* Ap = (const float4*)(A + (size_t)(w * 64 + l) * 16);
  const float4 a0 = Ap[0], a1 = Ap[1], a2 = Ap[2], a3 = Ap[3];
  auto sq = [](float4 a, float4 b) {
    const float dx = a.x - b.x, dy = a.y - b.y, dz = a.z - b.z, dw = a.w - b.w;
    return fmaf(dx, dx, fmaf(dy, dy, fmaf(dz, dz, dw * dw)));
  };
  u32 hp[4];
#pragma unroll
  for (int pr = 0; pr < 4; ++pr) {
    float dv[2];
#pragma unroll
    for (int h = 0; h < 2; ++h) {
      const int q = pr * 2 + h;
      const int s = grp * kG + q + 1;
      const int jb = min(max(s - l - 1, 0), kN - 1);
      const float4* Bp = (const float4*)(B + (size_t)jb * 16);
      dv[h] = (sq(a0, Bp[0]) + sq(a1, Bp[1]) + sq(a2, Bp[2]) + sq(a3, Bp[3])) * kLog2e;
    }
    hp[pr] = ((u32)__half_as_ushort(__float2half(dv[1])) << 16)
           |  (u32)__half_as_ushort(__float2half(dv[0]));
  }
  Et[((size_t)w * kGroups + grp) * 64 + l] = make_uint4(hp[0], hp[1], hp[2], hp[3]);
}

template <bool MASK>
__device__ __forceinline__ void run(
    int gBeg, int gEnd, int l, int v, int b,
    const uint4* __restrict__ EtL,
    const u32* __restrict__ gin, u32* __restrict__ gout,
    const u32* __restrict__ lin, u32* __restrict__ lout,
    float& mp, float& wp, float& mdm, float& wdm,
    u32 (&c)[2][kG], uint4 (&e4)[4],
    float* __restrict__ out) {
  const bool consG    = (v == 0) && (b > 0);
  const bool consNone = (v == 0) && (b == 0);
  const bool consL    = (v > 0);
  const bool prodL    = (v < kWaves - 1);
  const bool prodG    = (v == kWaves - 1) && (b < kBlocks - 1);
  const bool isL0  = (l == 0);
  const bool isL63 = (l == kLanes - 1);

  for (int g4 = gBeg; g4 < gEnd; g4 += 4) {
#pragma unroll
    for (int ph = 0; ph < 4; ++ph) {
      const int g = g4 + ph;
      const int ri = g & 1;                     // ring phase
      const int ei = g & 3;                     // Et phase

      // ---- verify this group's poll slots (wave-uniform; rare slow path) ----
      if (!consNone) {
        u32 mm = c[ri][0];
#pragma unroll
        for (int q = 1; q < kG; ++q) mm = mm > c[ri][q] ? mm : c[ri][q];
        if (__builtin_expect(mm == kSent, 0)) {
#pragma unroll
          for (int q = 0; q < kG; ++q) {
            const int e = g * kG + q;
            if (!MASK || e < kN) {
              u32 vv = c[ri][q];
              if (consG) {
                while (vv == kSent) {
#if __has_builtin(__builtin_amdgcn_s_sleep)
                  __builtin_amdgcn_s_sleep(1);
#endif
                  vv = aloadG(gin + e);
                }
              } else {
                while (vv == kSent) vv = aloadL(lin + e);
              }
              c[ri][q] = vv;
            }
          }
        }
      }

      // ---- 8 cells ----
      const u32 ecs[4] = {e4[ei].x, e4[ei].y, e4[ei].z, e4[ei].w};
#pragma unroll
      for (int q = 0; q < kG; ++q) {
        const int s = g * kG + q + 1;
        // up pair from lane l-1; lane 0 injects (r, 1)
        float mu_ = dppShr1f(mp);
        float wu_ = dppShr1f(wp);
        const float injm = consNone ? kBigP : __uint_as_float(c[ri][q]);
        mu_ = isL0 ? injm : mu_;
        wu_ = isL0 ? 1.0f : wu_;

        u32 hw = ecs[q >> 1];
        if (q & 1) hw >>= 16;
        const float dpv = __half2float(__ushort_as_half((unsigned short)(hw & 0xFFFFu)));

        const float mu = fminf(fminf(mu_, mdm), mp);     // v_min3
        const float pu = EXP2F(mu - mu_);
        const float pd = EXP2F(mu - mdm);
        const float pl = EXP2F(mu - mp);
        float wn = fmaf(wu_, pu, fmaf(wdm, pd, wp * pl));
        float mn = dpv + mu;
        if (MASK) {
          const int j = s - l;
          const bool jv = (j >= 1) && (j <= kN);
          mn = jv ? mn : kBigP;
          wn = jv ? wn : 1.0f;
        }
        mdm = mu_; wdm = wu_;
        mp = mn; wp = wn;

        if (prodL || prodG) {
          const float r = mn - LOG2F(wn);        // fold for publish (off-chain)
          if (isL63) {
            int e = s - kLanes;
            if (MASK) { const bool ok = (e >= 0) && (e < kN); e = ok ? e : kSMax; }
            if (prodL) astoreL(const_cast<u32*>(lout) + e, __float_as_uint(r));
            else       astoreG(gout + e, __float_as_uint(r));
          }
        } else if (MASK) {
          if (isL63 && s == kN + kLanes - 1)
            out[0] = (mn - LOG2F(wn)) * kLn2;    // R[4096,4096]
        }
      }

      // ---- fold state every 4 groups (w <= 3^65 stays in fp32 range) ----
      if (ph == 3) {
        mp  += LOG2F(wp);  wp  = 1.0f;
        mdm += LOG2F(wdm); wdm = 1.0f;
      }

      // ---- prefetch: ring for g+2 (same parity), Et for g+4 ----
      {
        const int gr = g + 2;
        const int eb = gr * kG;                  // <= 4168, in-ring
        if (consG) {
#pragma unroll
          for (int q = 0; q < kG; ++q) c[ri][q] = aloadG(gin + eb + q);
        } else if (consL) {
#pragma unroll
          for (int q = 0; q < kG; ++q) c[ri][q] = aloadL(lin + eb + q);
        }
        const int ge = g + 4;
        const int gc = ge < kGroups ? ge : kGroups - 1;
        e4[ei] = EtL[(size_t)gc * 64];
      }
      // Pin the prefetch issues here: don't let them sink past the next
      // group's verify (that would turn the verify wait into a full-latency
      // drain of just-issued loads every group).
      SCHED_FENCE();
    }
  }
}

__global__ __launch_bounds__(kWaves * kLanes) void sdtw_dp(const uint4* __restrict__ Et,
                                                           u32* __restrict__ gring,
                                                           float* __restrict__ out) {
  const int tid = threadIdx.x;
  const int v = tid >> 6, l = tid & 63;
  const int b = blockIdx.x;
  const int W = b * kWaves + v;                 // band 0..63 (row = 64W + l + 1)

  __shared__ u32 ring[kLdsTot];
  for (int i = tid; i < kLdsTot; i += kWaves * kLanes) ring[i] = kSent;
  __syncthreads();

  const uint4* EtL = Et + (size_t)W * kGroups * 64 + l;
  const u32* gin = gring + (size_t)(b > 0 ? b - 1 : 0) * kGRS;
  u32* gout = gring + (size_t)(b < kBlocks - 1 ? b : 0) * kGRS;
  const u32* lin = ring + (v > 0 ? v - 1 : 0) * kLRS;
  u32* lout = ring + (v < kWaves - 1 ? v : 0) * kLRS;

  // state pairs: left (mp,wp), diag (mdm,wdm); R' = m - log2(w)
  float mp  = kBigP, wp  = 1.0f;
  float mdm = (W == 0 && l == 0) ? 0.0f : kBigP;
  float wdm = 1.0f;

  const bool consG = (v == 0) && (b > 0);
  const bool consL = (v > 0);
  u32 c[2][kG];
  uint4 e4[4];
#pragma unroll
  for (int ph = 0; ph < 4; ++ph) e4[ph] = EtL[(size_t)ph * 64];
#pragma unroll
  for (int ri = 0; ri < 2; ++ri) {
#pragma unroll
    for (int q = 0; q < kG; ++q) {
      const int e = ri * kG + q;
      u32 val = __float_as_uint(kBigP);
      if (consG)      val = aloadG(gin + e);
      else if (consL) val = aloadL(lin + e);
      c[ri][q] = val;
    }
  }

  run<true >(0,   8,       l, v, b, EtL, gin, gout, lin, lout, mp, wp, mdm, wdm, c, e4, out);
  run<false>(8,   512,     l, v, b, EtL, gin, gout, lin, lout, mp, wp, mdm, wdm, c, e4, out);
  run<true >(512, kGroups, l, v, b, EtL, gin, gout, lin, lout, mp, wp, mdm, wdm, c, e4, out);
}

extern "C" void kernel_launch(void* const* d_in, const int* in_sizes, int n_in,
                              void* d_out, int out_size, void* d_ws, size_t ws_size,
                              hipStream_t stream) {
  const float* A = (const float*)d_in[0];
  const float* B = (const float*)d_in[1];
  float* out = (float*)d_out;

  u32* gring = (u32*)d_ws;
  uint4* Et = (uint4*)(gring + kGRTot);
  // ws need: 15*4224*4 B + 64*520*64*16 B ~= 0.25 MB + 34.1 MB (fits, per R2)

  sdtw_prep<<<dim3(kGroups / 4, 64), 256, 0, stream>>>(A, B, Et, gring);
  sdtw_dp<<<kBlocks, kWaves * kLanes, 0, stream>>>(Et, gring, out);
}